// Round 15
// baseline (157.412 us; speedup 1.0000x reference)
//
#include <hip/hip_runtime.h>

typedef unsigned short u16;
typedef __attribute__((ext_vector_type(8))) short bf16x8;
typedef __attribute__((ext_vector_type(4))) float f32x4;
typedef __attribute__((ext_vector_type(4))) unsigned short us4;

#define B_ 2
#define S_ 2048
#define D_ 1024
#define H_ 16
#define DH_ 64
#define M_ 4096 /* B*S */

__device__ __forceinline__ u16 f2bf(float f) {
  unsigned int u = __builtin_bit_cast(unsigned int, f);
  u += 0x7FFFu + ((u >> 16) & 1u);   // RNE
  return (u16)(u >> 16);
}

__device__ __forceinline__ unsigned int cvtpk(float lo, float hi) {
  unsigned int r;
  asm("v_cvt_pk_bf16_f32 %0, %1, %2" : "=v"(r) : "v"(lo), "v"(hi));
  return r;
}

__device__ __forceinline__ float fexp2(float x) {  // v_exp_f32 IS exp2
  float r;
  asm("v_exp_f32 %0, %1" : "=v"(r) : "v"(x));
  return r;
}

__device__ __forceinline__ void gload_lds16(const void* g, void* l) {
  __builtin_amdgcn_global_load_lds(
      (__attribute__((address_space(1))) void*)(g),
      (__attribute__((address_space(3))) void*)(l),
      16, 0, 0);
}

// ---------------- prep: weights only — W[z] [K][N] fp32 -> Wt[z] [N][K] bf16 ---------
__global__ __launch_bounds__(256) void wprep_kernel(const float* __restrict__ W0,
                                                    const float* __restrict__ W1,
                                                    const float* __restrict__ W2,
                                                    const float* __restrict__ W3,
                                                    u16* __restrict__ Wt) {
  __shared__ float tile[32][33];
  int z = blockIdx.z;
  const float* W = (z == 0) ? W0 : (z == 1) ? W1 : (z == 2) ? W2 : W3;
  u16* out = Wt + (size_t)z * D_ * D_;
  int tx = threadIdx.x, ty = threadIdx.y;
  int x = blockIdx.x * 32 + tx;
  for (int j = 0; j < 32; j += 8)
    tile[ty + j][tx] = W[(size_t)(blockIdx.y * 32 + ty + j) * D_ + x];
  __syncthreads();
  int x2 = blockIdx.y * 32 + tx;
  for (int j = 0; j < 32; j += 8)
    out[(size_t)(blockIdx.x * 32 + ty + j) * D_ + x2] = f2bf(tile[tx][ty + j]);
}

// ---------------- QKV GEMM: fp32 A staged raw via gload_lds (XOR-swizzled), ----------
// converted to bf16 at fragment-read time (ds_read_b128 x2 + cvt_pk x4). Kills the
// separate activation cvt pass. B (bf16 Wt) path unchanged. XCD-aware A-panel grid.
// z=2 (V) writes key columns PERMUTED within 64-key groups (attn PV b128 layout):
// kl -> ((kl>>5)&1)*32 + ((kl>>2)&3)*8 + ((kl>>4)&1)*4 + (kl&3).
__global__ __launch_bounds__(256) void gemm_qkv(const float* __restrict__ qin,
                                                const float* __restrict__ kin,
                                                const float* __restrict__ vin,
                                                const u16* __restrict__ Wt,
                                                const float* __restrict__ bq,
                                                const float* __restrict__ bk,
                                                const float* __restrict__ bv,
                                                u16* __restrict__ Qh,
                                                u16* __restrict__ Kh,
                                                u16* __restrict__ Vt) {
  __shared__ __align__(16) char AsfB[128 * 32 * 4];  // 16 KB fp32 A tile (swizzled)
  __shared__ u16 Bs[128 * 32];                       // 8 KB bf16 B tile
  int fid = blockIdx.x;
  int xcd = fid & 7, ii = fid >> 3;
  int grp = ii >> 3, yy = ii & 7;
  int gg = xcd * 12 + grp;
  int z = gg >> 5;
  int xx = gg & 31;
  const float* A = (z == 0) ? qin : (z == 1) ? kin : vin;
  const u16* Bt = Wt + (size_t)z * D_ * D_;
  const float* bias = (z == 0) ? bq : (z == 1) ? bk : bv;
  u16* O = (z == 0) ? Qh : (z == 1) ? Kh : Vt;

  int tid = threadIdx.x;
  int lane = tid & 63, wave = tid >> 6;
  int m0 = xx * 128, n0 = yy * 128;
  int wr = wave >> 1, wc = wave & 1;
  int fr = lane & 15, fk = (lane >> 4) * 8;

  f32x4 acc[4][4];
  const f32x4 vzero = {0.f, 0.f, 0.f, 0.f};
  for (int i = 0; i < 4; ++i)
    for (int j = 0; j < 4; ++j) acc[i][j] = vzero;

  for (int k0 = 0; k0 < D_; k0 += 32) {
    if (k0) __syncthreads();
    // A: 16 KB fp32, 4 passes; source col pre-swizzled (involution with read XOR)
    for (int i = 0; i < 4; ++i) {
      int lin = ((i * 4 + wave) << 10) + lane * 16;   // byte offset in tile
      int row = lin >> 7;                             // 128 B per fp32 row
      int colb = lin & 127;
      int scolb = colb ^ ((row & 7) << 4);
      gload_lds16(A + (size_t)(m0 + row) * D_ + k0 + (scolb >> 2),
                  AsfB + ((i * 4 + wave) << 10));
    }
    // B: 8 KB bf16, 2 passes (m97 pattern)
    for (int i = 0; i < 2; ++i) {
      int wofs = ((i * 4 + wave) << 10);
      int ofs = wofs + lane * 16;
      int row = ofs >> 6;
      int cole = (ofs & 63) >> 1;
      gload_lds16(Bt + (size_t)(n0 + row) * D_ + k0 + cole, (char*)Bs + wofs);
    }
    __syncthreads();
    bf16x8 af[4], bfr[4];
    for (int mi = 0; mi < 4; ++mi) {
      int row = wr * 64 + mi * 16 + fr;
      const char* base = AsfB + row * 128;
      int swz = (row & 7) << 4;
      f32x4 a0 = *(const f32x4*)(base + ((fk * 4) ^ swz));
      f32x4 a1 = *(const f32x4*)(base + ((fk * 4 + 16) ^ swz));
      union { unsigned int w4[4]; bf16x8 v; } af_;
      af_.w4[0] = cvtpk(a0[0], a0[1]);
      af_.w4[1] = cvtpk(a0[2], a0[3]);
      af_.w4[2] = cvtpk(a1[0], a1[1]);
      af_.w4[3] = cvtpk(a1[2], a1[3]);
      af[mi] = af_.v;
    }
    for (int ni = 0; ni < 4; ++ni)
      bfr[ni] = *(const bf16x8*)(Bs + (wc * 64 + ni * 16 + fr) * 32 + fk);
    for (int mi = 0; mi < 4; ++mi)
      for (int ni = 0; ni < 4; ++ni)
        acc[mi][ni] =
            __builtin_amdgcn_mfma_f32_16x16x32_bf16(af[mi], bfr[ni], acc[mi][ni], 0, 0, 0);
  }

  if (z == 2) {  // Vt [B][H][DH][S], key columns permuted within 64-key groups
    for (int mi = 0; mi < 4; ++mi) {
      int rowb = m0 + wr * 64 + mi * 16 + (lane >> 4) * 4;
      int bb2 = rowb >> 11, s0 = rowb & (S_ - 1);
      int l0 = s0 & 63;
      int p_local = ((l0 >> 5) & 1) * 32 + ((l0 >> 2) & 3) * 8 + ((l0 >> 4) & 1) * 4;
      int col2 = (s0 & ~63) | p_local;   // s0%4==0 -> 4 consecutive keys stay together
      for (int ni = 0; ni < 4; ++ni) {
        int col = n0 + wc * 64 + ni * 16 + fr;
        int hh = col >> 6, dh = col & 63;
        float bv = bias[col];
        us4 pk;
        for (int r = 0; r < 4; ++r) pk[r] = f2bf(acc[mi][ni][r] + bv);
        *(us4*)(O + ((size_t)(bb2 * H_ + hh) * DH_ + dh) * S_ + col2) = pk;
      }
    }
  } else {       // Qh/Kh [B][H][S][DH]
    float scale = (z == 0) ? 0.125f : 1.0f;
    for (int mi = 0; mi < 4; ++mi) {
      int rowb = m0 + wr * 64 + mi * 16 + (lane >> 4) * 4;
      for (int ni = 0; ni < 4; ++ni) {
        int col = n0 + wc * 64 + ni * 16 + fr;
        int hh = col >> 6, dh = col & 63;
        float bv = bias[col];
        for (int r = 0; r < 4; ++r) {
          int row = rowb + r;
          int bb2 = row >> 11, s = row & (S_ - 1);
          O[((size_t)(bb2 * H_ + hh) * S_ + s) * DH_ + dh] =
              f2bf((acc[mi][ni][r] + bv) * scale);
        }
      }
    }
  }
}

// ---------------- output GEMM: BM=64 x BN=128, XCD-aware A-panel grouping ------------
__global__ __launch_bounds__(256) void gemm_out(const u16* __restrict__ A,
                                                const u16* __restrict__ Bt,
                                                const float* __restrict__ bias,
                                                float* __restrict__ O) {
  __shared__ u16 As[64 * 32];
  __shared__ u16 Bs[128 * 32];
  int fid = blockIdx.x;
  int xcd = fid & 7, ii = fid >> 3;
  int grp = ii >> 3, yy = ii & 7;
  int gg = xcd * 8 + grp;
  int tid = threadIdx.x;
  int lane = tid & 63, wave = tid >> 6;
  int m0 = gg * 64, n0 = yy * 128;
  int fr = lane & 15, fk = (lane >> 4) * 8;

  f32x4 acc[4][2];
  const f32x4 vzero = {0.f, 0.f, 0.f, 0.f};
  for (int i = 0; i < 4; ++i)
    for (int j = 0; j < 2; ++j) acc[i][j] = vzero;

  for (int k0 = 0; k0 < D_; k0 += 32) {
    if (k0) __syncthreads();
    {
      int wofs = wave << 10;
      int ofs = wofs + lane * 16;
      int row = ofs >> 6;
      int cole = (ofs & 63) >> 1;
      gload_lds16(A + (size_t)(m0 + row) * D_ + k0 + cole, (char*)As + wofs);
    }
    for (int i = 0; i < 2; ++i) {
      int wofs = ((i * 4 + wave) << 10);
      int ofs = wofs + lane * 16;
      int row = ofs >> 6;
      int cole = (ofs & 63) >> 1;
      gload_lds16(Bt + (size_t)(n0 + row) * D_ + k0 + cole, (char*)Bs + wofs);
    }
    __syncthreads();
    bf16x8 af[4], bfr[2];
    for (int mi = 0; mi < 4; ++mi)
      af[mi] = *(const bf16x8*)(As + (mi * 16 + fr) * 32 + fk);
    for (int ni = 0; ni < 2; ++ni)
      bfr[ni] = *(const bf16x8*)(Bs + (wave * 32 + ni * 16 + fr) * 32 + fk);
    for (int mi = 0; mi < 4; ++mi)
      for (int ni = 0; ni < 2; ++ni)
        acc[mi][ni] =
            __builtin_amdgcn_mfma_f32_16x16x32_bf16(af[mi], bfr[ni], acc[mi][ni], 0, 0, 0);
  }

  for (int mi = 0; mi < 4; ++mi) {
    int rowb = m0 + mi * 16 + (lane >> 4) * 4;
    for (int ni = 0; ni < 2; ++ni) {
      int col = n0 + wave * 32 + ni * 16 + fr;
      float bv = bias[col];
      for (int r = 0; r < 4; ++r)
        O[(size_t)(rowb + r) * D_ + col] = acc[mi][ni][r] + bv;
    }
  }
}

// ---------------- flash attention v10 (unchanged from round 14) ----------------
__global__ __launch_bounds__(256, 4) void attn_kernel(const u16* __restrict__ Qh,
                                                      const u16* __restrict__ Kh,
                                                      const u16* __restrict__ Vt,
                                                      const float* __restrict__ relb,
                                                      u16* __restrict__ attnout) {
  __shared__ u16 KVs[2][2][4096];  // [kind][buf][64x64 bf16] = 32 KB

  int fid = blockIdx.x;
  int rr = fid >> 8, c = fid & 255;
  int j = c >> 3, e = c & 7;
  int s = (rr & 1) ? j : 31 - j;
  int h = (rr & 1) ? e + 8 : e;
  int b = rr >> 1;

  int w = threadIdx.x >> 6, lane = threadIdx.x & 63;
  int fr = lane & 15, g = lane >> 4;
  int q0w = s * 64 + w * 16;
  int qme = q0w + fr;
  int bh = b * H_ + h;
  int sx = (fr & 7) << 4;            // read-side XOR swizzle (bytes)

  int kind = w >> 1;
  int i0 = (w & 1) * 4;
  int srow_lo = lane >> 3;
  int scb = (lane & 7) * 16;

  const u16* Qb = Qh + ((size_t)bh * S_ + q0w) * DH_;
  bf16x8 qf0 = *(const bf16x8*)(Qb + fr * DH_ + 8 * g);
  bf16x8 qf1 = *(const bf16x8*)(Qb + fr * DH_ + 32 + 8 * g);

  const float* Bq = relb + (size_t)h * S_ * S_ + (size_t)qme * S_ + 4 * g;
  const float LOG2E = 1.44269504f;

  int T = s + 1;

  auto STAGE = [&](int buf, int kb) {
    for (int i = 0; i < 4; ++i) {
      int ii = i0 + i;
      int row = ii * 8 + srow_lo;
      int cbs = scb ^ ((row & 7) << 4);
      const u16* src;
      if (kind == 0)
        src = Kh + ((size_t)bh * S_ + kb + row) * DH_ + (cbs >> 1);
      else
        src = Vt + ((size_t)bh * DH_ + row) * S_ + kb + (cbs >> 1);
      gload_lds16(src, &KVs[kind][buf][ii * 512]);
    }
  };

  f32x4 acc[4];
  const f32x4 vzero = {0.f, 0.f, 0.f, 0.f};
  for (int f4 = 0; f4 < 4; ++f4) acc[f4] = vzero;
  float m = -1.0e4f, l = 0.f;   // per-lane partial l; first tile always rescales

  STAGE(0, 0);
  f32x4 bi[4], bn[4];
  for (int cc = 0; cc < 4; ++cc) bi[cc] = *(const f32x4*)(Bq + 16 * cc);
  __syncthreads();

  for (int t = 0; t < T; ++t) {
    int kb = t * 64;
    int buf = t & 1;
    bool diag = (t == T - 1);
    if (!diag) {
      STAGE(buf ^ 1, kb + 64);
      for (int cc = 0; cc < 4; ++cc) bn[cc] = *(const f32x4*)(Bq + kb + 64 + 16 * cc);
    }

    const u16* Kt = &KVs[0][buf][0];
    const u16* Vl = &KVs[1][buf][0];

    // swapped QK^T with bias as the C operand
    f32x4 sc[4];
    __builtin_amdgcn_s_setprio(1);
    for (int cc = 0; cc < 4; ++cc) {
      bf16x8 k0 = *(const bf16x8*)(Kt + (16 * cc + fr) * 64 + (((16 * g) ^ sx) >> 1));
      bf16x8 k1 = *(const bf16x8*)(Kt + (16 * cc + fr) * 64 + (((64 + 16 * g) ^ sx) >> 1));
      f32x4 z = __builtin_amdgcn_mfma_f32_16x16x32_bf16(k0, qf0, bi[cc], 0, 0, 0);
      z = __builtin_amdgcn_mfma_f32_16x16x32_bf16(k1, qf1, z, 0, 0, 0);
      sc[cc] = z;
    }
    __builtin_amdgcn_s_setprio(0);
    if (diag) {  // only the diagonal tile needs causal masking (bias already in)
      for (int cc = 0; cc < 4; ++cc)
        for (int r = 0; r < 4; ++r) {
          int key = kb + 16 * cc + 4 * g + r;
          sc[cc][r] = (key <= qme) ? sc[cc][r] : -1e30f;
        }
    }
    float pm = sc[0][0];
    for (int cc = 0; cc < 4; ++cc)
      for (int r = 0; r < 4; ++r) pm = fmaxf(pm, sc[cc][r]);
    pm = fmaxf(pm, __shfl_xor(pm, 16));
    pm = fmaxf(pm, __shfl_xor(pm, 32));
    if (!__all(pm - m <= 8.0f)) {
      float mn = fmaxf(m, pm);
      float corr = __expf(m - mn);
      m = mn;
      l *= corr;
      float c0 = __shfl(corr, 4 * g + 0);
      float c1 = __shfl(corr, 4 * g + 1);
      float c2 = __shfl(corr, 4 * g + 2);
      float c3 = __shfl(corr, 4 * g + 3);
      for (int f4 = 0; f4 < 4; ++f4) {
        acc[f4][0] *= c0; acc[f4][1] *= c1; acc[f4][2] *= c2; acc[f4][3] *= c3;
      }
    }
    float nms = m * -LOG2E;
    float rs = 0.f;
    for (int cc = 0; cc < 4; ++cc)
      for (int r = 0; r < 4; ++r) {
        sc[cc][r] = fexp2(fmaf(sc[cc][r], LOG2E, nms));
        rs += sc[cc][r];
      }
    l += rs;
    union { unsigned int w4[4]; bf16x8 v; } pp[2];
    for (int jj = 0; jj < 2; ++jj) {
      pp[jj].w4[0] = cvtpk(sc[2 * jj][0], sc[2 * jj][1]);
      pp[jj].w4[1] = cvtpk(sc[2 * jj][2], sc[2 * jj][3]);
      pp[jj].w4[2] = cvtpk(sc[2 * jj + 1][0], sc[2 * jj + 1][1]);
      pp[jj].w4[3] = cvtpk(sc[2 * jj + 1][2], sc[2 * jj + 1][3]);
    }
    // PV: V pre-permuted -> one b128 per (f4, jj), conflict-free
    __builtin_amdgcn_s_setprio(1);
    for (int f4 = 0; f4 < 4; ++f4) {
      for (int jj = 0; jj < 2; ++jj) {
        bf16x8 vv = *(const bf16x8*)(Vl + (f4 * 16 + fr) * 64 +
                                     (((jj * 64 + g * 16) ^ sx) >> 1));
        acc[f4] = __builtin_amdgcn_mfma_f32_16x16x32_bf16(pp[jj].v, vv, acc[f4], 0, 0, 0);
      }
    }
    __builtin_amdgcn_s_setprio(0);
    for (int cc = 0; cc < 4; ++cc) bi[cc] = bn[cc];
    __syncthreads();
  }

  // epilogue: reduce per-lane partial l across the 4 lanes sharing each q-row
  l += __shfl_xor(l, 16);
  l += __shfl_xor(l, 32);
  float il = 1.f / l;
  for (int r = 0; r < 4; ++r) {
    float ilr = __shfl(il, 4 * g + r);
    int qq = q0w + 4 * g + r;
    u16* ob = attnout + ((size_t)b * S_ + qq) * D_ + h * 64;
    for (int f4 = 0; f4 < 4; ++f4) ob[f4 * 16 + fr] = f2bf(acc[f4][r] * ilr);
  }
}

extern "C" void kernel_launch(void* const* d_in, const int* in_sizes, int n_in,
                              void* d_out, int out_size, void* d_ws, size_t ws_size,
                              hipStream_t stream) {
  const float* q = (const float*)d_in[0];
  const float* k = (const float*)d_in[1];
  const float* v = (const float*)d_in[2];
  const float* rb = (const float*)d_in[4];
  const float* Wq = (const float*)d_in[5];
  const float* bq = (const float*)d_in[6];
  const float* Wk = (const float*)d_in[7];
  const float* bk = (const float*)d_in[8];
  const float* Wv = (const float*)d_in[9];
  const float* bv = (const float*)d_in[10];
  const float* Wo = (const float*)d_in[11];
  const float* bo = (const float*)d_in[12];
  float* out = (float*)d_out;

  char* ws = (char*)d_ws;
  const size_t SZ = (size_t)M_ * D_ * 2;  // 8.39 MB
  u16* Xb = (u16*)(ws);                   // attn output (bf16 [M][D])
  u16* Qh = (u16*)(ws + SZ);
  u16* Kh = (u16*)(ws + 2 * SZ);
  u16* Vt = (u16*)(ws + 3 * SZ);
  u16* Wt = (u16*)(ws + 4 * SZ);          // 4 transposed bf16 weights (8.39 MB)

  // 1. weight transpose+cvt only (activation cvt now fused into gemm_qkv)
  wprep_kernel<<<dim3(32, 32, 4), dim3(32, 8), 0, stream>>>(Wq, Wk, Wv, Wo, Wt);

  // 2. QKV projection straight from fp32 activations
  gemm_qkv<<<dim3(768), 256, 0, stream>>>(q, k, v, Wt, bq, bk, bv, Qh, Kh, Vt);

  // 3. attention
  attn_kernel<<<dim3(1024), 256, 0, stream>>>(Qh, Kh, Vt, rb, Xb);

  // 4. output projection
  gemm_out<<<dim3(512), 256, 0, stream>>>(Xb, Wt + 3 * (size_t)D_ * D_, bo, out);
}

// Round 16
// 140.200 us; speedup vs baseline: 1.1228x; 1.1228x over previous
//
#include <hip/hip_runtime.h>

typedef unsigned short u16;
typedef __attribute__((ext_vector_type(8))) short bf16x8;
typedef __attribute__((ext_vector_type(4))) float f32x4;
typedef __attribute__((ext_vector_type(4))) unsigned short us4;

#define B_ 2
#define S_ 2048
#define D_ 1024
#define H_ 16
#define DH_ 64
#define M_ 4096 /* B*S */

__device__ __forceinline__ u16 f2bf(float f) {
  unsigned int u = __builtin_bit_cast(unsigned int, f);
  u += 0x7FFFu + ((u >> 16) & 1u);   // RNE
  return (u16)(u >> 16);
}

__device__ __forceinline__ unsigned int cvtpk(float lo, float hi) {
  unsigned int r;
  asm("v_cvt_pk_bf16_f32 %0, %1, %2" : "=v"(r) : "v"(lo), "v"(hi));
  return r;
}

__device__ __forceinline__ float fexp2(float x) {  // v_exp_f32 IS exp2
  float r;
  asm("v_exp_f32 %0, %1" : "=v"(r) : "v"(x));
  return r;
}

__device__ __forceinline__ void gload_lds16(const void* g, void* l) {
  __builtin_amdgcn_global_load_lds(
      (__attribute__((address_space(1))) void*)(g),
      (__attribute__((address_space(3))) void*)(l),
      16, 0, 0);
}

// ---------------- prep: z<4 -> W[z] transpose+cvt; z>=4 -> q/k/v fp32->bf16 ----------
__global__ __launch_bounds__(256) void wprep_kernel(const float* __restrict__ W0,
                                                    const float* __restrict__ W1,
                                                    const float* __restrict__ W2,
                                                    const float* __restrict__ W3,
                                                    u16* __restrict__ Wt,
                                                    const float* __restrict__ qin,
                                                    const float* __restrict__ kin,
                                                    const float* __restrict__ vin,
                                                    u16* __restrict__ Xq,
                                                    u16* __restrict__ Xk,
                                                    u16* __restrict__ Xv) {
  int z = blockIdx.z;
  if (z < 4) {
    __shared__ float tile[32][33];
    const float* W = (z == 0) ? W0 : (z == 1) ? W1 : (z == 2) ? W2 : W3;
    u16* out = Wt + (size_t)z * D_ * D_;
    int tx = threadIdx.x, ty = threadIdx.y;
    int x = blockIdx.x * 32 + tx;
    for (int j = 0; j < 32; j += 8)
      tile[ty + j][tx] = W[(size_t)(blockIdx.y * 32 + ty + j) * D_ + x];
    __syncthreads();
    int x2 = blockIdx.y * 32 + tx;
    for (int j = 0; j < 32; j += 8)
      out[(size_t)(blockIdx.x * 32 + ty + j) * D_ + x2] = f2bf(tile[tx][ty + j]);
  } else {
    int zz = z - 4;
    const float* src = (zz == 0) ? qin : (zz == 1) ? kin : vin;
    u16* dst = (zz == 0) ? Xq : (zz == 1) ? Xk : Xv;
    int bid = blockIdx.y * 32 + blockIdx.x;
    int t = threadIdx.y * 32 + threadIdx.x;
    const float4* s4 = (const float4*)src;
    for (int i = 0; i < 4; ++i) {
      int idx = bid * 1024 + i * 256 + t;
      float4 v4 = s4[idx];
      us4 o;
      o[0] = f2bf(v4.x); o[1] = f2bf(v4.y); o[2] = f2bf(v4.z); o[3] = f2bf(v4.w);
      ((us4*)dst)[idx] = o;
    }
  }
}

// ---------------- QKV GEMM, m97 staging + XCD-aware A-panel grouping ----------------
// z=2 (V) writes the key dimension PERMUTED within each 64-key group so the attn
// PV B-fragments are contiguous 16B: local key kl -> pos = ((kl>>5)&1)*32 +
// ((kl>>2)&3)*8 + ((kl>>4)&1)*4 + (kl&3). The us4 write stays contiguous.
__global__ __launch_bounds__(256) void gemm_qkv(const u16* __restrict__ Xq,
                                                const u16* __restrict__ Xk,
                                                const u16* __restrict__ Xv,
                                                const u16* __restrict__ Wt,
                                                const float* __restrict__ bq,
                                                const float* __restrict__ bk,
                                                const float* __restrict__ bv,
                                                u16* __restrict__ Qh,
                                                u16* __restrict__ Kh,
                                                u16* __restrict__ Vt) {
  __shared__ u16 As[128 * 32];
  __shared__ u16 Bs[128 * 32];
  int fid = blockIdx.x;
  int xcd = fid & 7, ii = fid >> 3;
  int grp = ii >> 3, yy = ii & 7;
  int gg = xcd * 12 + grp;
  int z = gg >> 5;
  int xx = gg & 31;
  const u16* A = (z == 0) ? Xq : (z == 1) ? Xk : Xv;
  const u16* Bt = Wt + (size_t)z * D_ * D_;
  const float* bias = (z == 0) ? bq : (z == 1) ? bk : bv;
  u16* O = (z == 0) ? Qh : (z == 1) ? Kh : Vt;

  int tid = threadIdx.x;
  int lane = tid & 63, wave = tid >> 6;
  int m0 = xx * 128, n0 = yy * 128;
  int wr = wave >> 1, wc = wave & 1;
  int fr = lane & 15, fk = (lane >> 4) * 8;

  f32x4 acc[4][4];
  const f32x4 vzero = {0.f, 0.f, 0.f, 0.f};
  for (int i = 0; i < 4; ++i)
    for (int j = 0; j < 4; ++j) acc[i][j] = vzero;

  for (int k0 = 0; k0 < D_; k0 += 32) {
    if (k0) __syncthreads();
    for (int i = 0; i < 2; ++i) {
      int wofs = ((i * 4 + wave) << 10);
      int ofs = wofs + lane * 16;
      int row = ofs >> 6;
      int cole = (ofs & 63) >> 1;
      gload_lds16(A + (size_t)(m0 + row) * D_ + k0 + cole, (char*)As + wofs);
      gload_lds16(Bt + (size_t)(n0 + row) * D_ + k0 + cole, (char*)Bs + wofs);
    }
    __syncthreads();
    bf16x8 af[4], bfr[4];
    for (int mi = 0; mi < 4; ++mi)
      af[mi] = *(const bf16x8*)(As + (wr * 64 + mi * 16 + fr) * 32 + fk);
    for (int ni = 0; ni < 4; ++ni)
      bfr[ni] = *(const bf16x8*)(Bs + (wc * 64 + ni * 16 + fr) * 32 + fk);
    for (int mi = 0; mi < 4; ++mi)
      for (int ni = 0; ni < 4; ++ni)
        acc[mi][ni] =
            __builtin_amdgcn_mfma_f32_16x16x32_bf16(af[mi], bfr[ni], acc[mi][ni], 0, 0, 0);
  }

  if (z == 2) {  // Vt [B][H][DH][S], key columns permuted within 64-key groups
    for (int mi = 0; mi < 4; ++mi) {
      int rowb = m0 + wr * 64 + mi * 16 + (lane >> 4) * 4;
      int bb2 = rowb >> 11, s0 = rowb & (S_ - 1);
      int l0 = s0 & 63;
      int p_local = ((l0 >> 5) & 1) * 32 + ((l0 >> 2) & 3) * 8 + ((l0 >> 4) & 1) * 4;
      int col2 = (s0 & ~63) | p_local;   // s0%4==0 -> 4 consecutive keys stay together
      for (int ni = 0; ni < 4; ++ni) {
        int col = n0 + wc * 64 + ni * 16 + fr;
        int hh = col >> 6, dh = col & 63;
        float bv = bias[col];
        us4 pk;
        for (int r = 0; r < 4; ++r) pk[r] = f2bf(acc[mi][ni][r] + bv);
        *(us4*)(O + ((size_t)(bb2 * H_ + hh) * DH_ + dh) * S_ + col2) = pk;
      }
    }
  } else {       // Qh/Kh [B][H][S][DH]
    float scale = (z == 0) ? 0.125f : 1.0f;
    for (int mi = 0; mi < 4; ++mi) {
      int rowb = m0 + wr * 64 + mi * 16 + (lane >> 4) * 4;
      for (int ni = 0; ni < 4; ++ni) {
        int col = n0 + wc * 64 + ni * 16 + fr;
        int hh = col >> 6, dh = col & 63;
        float bv = bias[col];
        for (int r = 0; r < 4; ++r) {
          int row = rowb + r;
          int bb2 = row >> 11, s = row & (S_ - 1);
          O[((size_t)(bb2 * H_ + hh) * S_ + s) * DH_ + dh] =
              f2bf((acc[mi][ni][r] + bv) * scale);
        }
      }
    }
  }
}

// ---------------- output GEMM: BM=64 x BN=128, XCD-aware A-panel grouping ------------
__global__ __launch_bounds__(256) void gemm_out(const u16* __restrict__ A,
                                                const u16* __restrict__ Bt,
                                                const float* __restrict__ bias,
                                                float* __restrict__ O) {
  __shared__ u16 As[64 * 32];
  __shared__ u16 Bs[128 * 32];
  int fid = blockIdx.x;
  int xcd = fid & 7, ii = fid >> 3;
  int grp = ii >> 3, yy = ii & 7;
  int gg = xcd * 8 + grp;
  int tid = threadIdx.x;
  int lane = tid & 63, wave = tid >> 6;
  int m0 = gg * 64, n0 = yy * 128;
  int fr = lane & 15, fk = (lane >> 4) * 8;

  f32x4 acc[4][2];
  const f32x4 vzero = {0.f, 0.f, 0.f, 0.f};
  for (int i = 0; i < 4; ++i)
    for (int j = 0; j < 2; ++j) acc[i][j] = vzero;

  for (int k0 = 0; k0 < D_; k0 += 32) {
    if (k0) __syncthreads();
    {
      int wofs = wave << 10;
      int ofs = wofs + lane * 16;
      int row = ofs >> 6;
      int cole = (ofs & 63) >> 1;
      gload_lds16(A + (size_t)(m0 + row) * D_ + k0 + cole, (char*)As + wofs);
    }
    for (int i = 0; i < 2; ++i) {
      int wofs = ((i * 4 + wave) << 10);
      int ofs = wofs + lane * 16;
      int row = ofs >> 6;
      int cole = (ofs & 63) >> 1;
      gload_lds16(Bt + (size_t)(n0 + row) * D_ + k0 + cole, (char*)Bs + wofs);
    }
    __syncthreads();
    bf16x8 af[4], bfr[2];
    for (int mi = 0; mi < 4; ++mi)
      af[mi] = *(const bf16x8*)(As + (mi * 16 + fr) * 32 + fk);
    for (int ni = 0; ni < 2; ++ni)
      bfr[ni] = *(const bf16x8*)(Bs + (wave * 32 + ni * 16 + fr) * 32 + fk);
    for (int mi = 0; mi < 4; ++mi)
      for (int ni = 0; ni < 2; ++ni)
        acc[mi][ni] =
            __builtin_amdgcn_mfma_f32_16x16x32_bf16(af[mi], bfr[ni], acc[mi][ni], 0, 0, 0);
  }

  for (int mi = 0; mi < 4; ++mi) {
    int rowb = m0 + mi * 16 + (lane >> 4) * 4;
    for (int ni = 0; ni < 2; ++ni) {
      int col = n0 + wave * 32 + ni * 16 + fr;
      float bv = bias[col];
      for (int r = 0; r < 4; ++r)
        O[(size_t)(rowb + r) * D_ + col] = acc[mi][ni][r] + bv;
    }
  }
}

// ---------------- flash attention v10: LDS-staged, b128 V reads ----------------
// Balanced grid (const 66 tiles/CU-slot, b-paired bias via L2), bias-as-C MFMA init,
// fma/exp2 softmax, per-lane partial l, diagonal-only masking, V pre-permuted so PV
// B-frags are single ds_read_b128 (conflict-free under the XOR swizzle).
__global__ __launch_bounds__(256, 4) void attn_kernel(const u16* __restrict__ Qh,
                                                      const u16* __restrict__ Kh,
                                                      const u16* __restrict__ Vt,
                                                      const float* __restrict__ relb,
                                                      u16* __restrict__ attnout) {
  __shared__ u16 KVs[2][2][4096];  // [kind][buf][64x64 bf16] = 32 KB

  int fid = blockIdx.x;
  int rr = fid >> 8, c = fid & 255;
  int j = c >> 3, e = c & 7;
  int s = (rr & 1) ? j : 31 - j;
  int h = (rr & 1) ? e + 8 : e;
  int b = rr >> 1;

  int w = threadIdx.x >> 6, lane = threadIdx.x & 63;
  int fr = lane & 15, g = lane >> 4;
  int q0w = s * 64 + w * 16;
  int qme = q0w + fr;
  int bh = b * H_ + h;
  int sx = (fr & 7) << 4;            // read-side XOR swizzle (bytes)

  int kind = w >> 1;
  int i0 = (w & 1) * 4;
  int srow_lo = lane >> 3;
  int scb = (lane & 7) * 16;

  const u16* Qb = Qh + ((size_t)bh * S_ + q0w) * DH_;
  bf16x8 qf0 = *(const bf16x8*)(Qb + fr * DH_ + 8 * g);
  bf16x8 qf1 = *(const bf16x8*)(Qb + fr * DH_ + 32 + 8 * g);

  const float* Bq = relb + (size_t)h * S_ * S_ + (size_t)qme * S_ + 4 * g;
  const float LOG2E = 1.44269504f;

  int T = s + 1;

  auto STAGE = [&](int buf, int kb) {
    for (int i = 0; i < 4; ++i) {
      int ii = i0 + i;
      int row = ii * 8 + srow_lo;
      int cbs = scb ^ ((row & 7) << 4);
      const u16* src;
      if (kind == 0)
        src = Kh + ((size_t)bh * S_ + kb + row) * DH_ + (cbs >> 1);
      else
        src = Vt + ((size_t)bh * DH_ + row) * S_ + kb + (cbs >> 1);
      gload_lds16(src, &KVs[kind][buf][ii * 512]);
    }
  };

  f32x4 acc[4];
  const f32x4 vzero = {0.f, 0.f, 0.f, 0.f};
  for (int f4 = 0; f4 < 4; ++f4) acc[f4] = vzero;
  float m = -1.0e4f, l = 0.f;   // per-lane partial l; first tile always rescales

  STAGE(0, 0);
  f32x4 bi[4], bn[4];
  for (int cc = 0; cc < 4; ++cc) bi[cc] = *(const f32x4*)(Bq + 16 * cc);
  __syncthreads();

  for (int t = 0; t < T; ++t) {
    int kb = t * 64;
    int buf = t & 1;
    bool diag = (t == T - 1);
    if (!diag) {
      STAGE(buf ^ 1, kb + 64);
      for (int cc = 0; cc < 4; ++cc) bn[cc] = *(const f32x4*)(Bq + kb + 64 + 16 * cc);
    }

    const u16* Kt = &KVs[0][buf][0];
    const u16* Vl = &KVs[1][buf][0];

    // swapped QK^T with bias as the C operand
    f32x4 sc[4];
    __builtin_amdgcn_s_setprio(1);
    for (int cc = 0; cc < 4; ++cc) {
      bf16x8 k0 = *(const bf16x8*)(Kt + (16 * cc + fr) * 64 + (((16 * g) ^ sx) >> 1));
      bf16x8 k1 = *(const bf16x8*)(Kt + (16 * cc + fr) * 64 + (((64 + 16 * g) ^ sx) >> 1));
      f32x4 z = __builtin_amdgcn_mfma_f32_16x16x32_bf16(k0, qf0, bi[cc], 0, 0, 0);
      z = __builtin_amdgcn_mfma_f32_16x16x32_bf16(k1, qf1, z, 0, 0, 0);
      sc[cc] = z;
    }
    __builtin_amdgcn_s_setprio(0);
    if (diag) {  // only the diagonal tile needs causal masking (bias already in)
      for (int cc = 0; cc < 4; ++cc)
        for (int r = 0; r < 4; ++r) {
          int key = kb + 16 * cc + 4 * g + r;
          sc[cc][r] = (key <= qme) ? sc[cc][r] : -1e30f;
        }
    }
    float pm = sc[0][0];
    for (int cc = 0; cc < 4; ++cc)
      for (int r = 0; r < 4; ++r) pm = fmaxf(pm, sc[cc][r]);
    pm = fmaxf(pm, __shfl_xor(pm, 16));
    pm = fmaxf(pm, __shfl_xor(pm, 32));
    if (!__all(pm - m <= 8.0f)) {
      float mn = fmaxf(m, pm);
      float corr = __expf(m - mn);
      m = mn;
      l *= corr;
      float c0 = __shfl(corr, 4 * g + 0);
      float c1 = __shfl(corr, 4 * g + 1);
      float c2 = __shfl(corr, 4 * g + 2);
      float c3 = __shfl(corr, 4 * g + 3);
      for (int f4 = 0; f4 < 4; ++f4) {
        acc[f4][0] *= c0; acc[f4][1] *= c1; acc[f4][2] *= c2; acc[f4][3] *= c3;
      }
    }
    float nms = m * -LOG2E;
    float rs = 0.f;
    for (int cc = 0; cc < 4; ++cc)
      for (int r = 0; r < 4; ++r) {
        sc[cc][r] = fexp2(fmaf(sc[cc][r], LOG2E, nms));
        rs += sc[cc][r];
      }
    l += rs;
    union { unsigned int w4[4]; bf16x8 v; } pp[2];
    for (int jj = 0; jj < 2; ++jj) {
      pp[jj].w4[0] = cvtpk(sc[2 * jj][0], sc[2 * jj][1]);
      pp[jj].w4[1] = cvtpk(sc[2 * jj][2], sc[2 * jj][3]);
      pp[jj].w4[2] = cvtpk(sc[2 * jj + 1][0], sc[2 * jj + 1][1]);
      pp[jj].w4[3] = cvtpk(sc[2 * jj + 1][2], sc[2 * jj + 1][3]);
    }
    // PV: V pre-permuted -> one b128 per (f4, jj), conflict-free
    __builtin_amdgcn_s_setprio(1);
    for (int f4 = 0; f4 < 4; ++f4) {
      for (int jj = 0; jj < 2; ++jj) {
        bf16x8 vv = *(const bf16x8*)(Vl + (f4 * 16 + fr) * 64 +
                                     (((jj * 64 + g * 16) ^ sx) >> 1));
        acc[f4] = __builtin_amdgcn_mfma_f32_16x16x32_bf16(pp[jj].v, vv, acc[f4], 0, 0, 0);
      }
    }
    __builtin_amdgcn_s_setprio(0);
    for (int cc = 0; cc < 4; ++cc) bi[cc] = bn[cc];
    __syncthreads();
  }

  // epilogue: reduce per-lane partial l across the 4 lanes sharing each q-row
  l += __shfl_xor(l, 16);
  l += __shfl_xor(l, 32);
  float il = 1.f / l;
  for (int r = 0; r < 4; ++r) {
    float ilr = __shfl(il, 4 * g + r);
    int qq = q0w + 4 * g + r;
    u16* ob = attnout + ((size_t)b * S_ + qq) * D_ + h * 64;
    for (int f4 = 0; f4 < 4; ++f4) ob[f4 * 16 + fr] = f2bf(acc[f4][r] * ilr);
  }
}

extern "C" void kernel_launch(void* const* d_in, const int* in_sizes, int n_in,
                              void* d_out, int out_size, void* d_ws, size_t ws_size,
                              hipStream_t stream) {
  const float* q = (const float*)d_in[0];
  const float* k = (const float*)d_in[1];
  const float* v = (const float*)d_in[2];
  const float* rb = (const float*)d_in[4];
  const float* Wq = (const float*)d_in[5];
  const float* bq = (const float*)d_in[6];
  const float* Wk = (const float*)d_in[7];
  const float* bk = (const float*)d_in[8];
  const float* Wv = (const float*)d_in[9];
  const float* bv = (const float*)d_in[10];
  const float* Wo = (const float*)d_in[11];
  const float* bo = (const float*)d_in[12];
  float* out = (float*)d_out;

  char* ws = (char*)d_ws;
  const size_t SZ = (size_t)M_ * D_ * 2;
  u16* Xq = (u16*)(ws);
  u16* Xk = (u16*)(ws + SZ);
  u16* Xv = (u16*)(ws + 2 * SZ);
  u16* Qh = (u16*)(ws + 3 * SZ);
  u16* Kh = (u16*)(ws + 4 * SZ);
  u16* Vt = (u16*)(ws + 5 * SZ);
  u16* Wt = (u16*)(ws + 6 * SZ);
  u16* Xb = Xq;

  wprep_kernel<<<dim3(32, 32, 7), dim3(32, 8), 0, stream>>>(Wq, Wk, Wv, Wo, Wt,
                                                            q, k, v, Xq, Xk, Xv);

  gemm_qkv<<<dim3(768), 256, 0, stream>>>(Xq, Xk, Xv, Wt, bq, bk, bv, Qh, Kh, Vt);

  attn_kernel<<<dim3(1024), 256, 0, stream>>>(Qh, Kh, Vt, rb, Xb);

  gemm_out<<<dim3(512), 256, 0, stream>>>(Xb, Wt + 3 * (size_t)D_ * D_, bo, out);
}

// Round 17
// 129.410 us; speedup vs baseline: 1.2164x; 1.0834x over previous
//
#include <hip/hip_runtime.h>

typedef unsigned short u16;
typedef __attribute__((ext_vector_type(8))) short bf16x8;
typedef __attribute__((ext_vector_type(4))) float f32x4;
typedef __attribute__((ext_vector_type(4))) unsigned short us4;

#define B_ 2
#define S_ 2048
#define D_ 1024
#define H_ 16
#define DH_ 64
#define M_ 4096 /* B*S */

__device__ __forceinline__ u16 f2bf(float f) {
  unsigned int u = __builtin_bit_cast(unsigned int, f);
  u += 0x7FFFu + ((u >> 16) & 1u);   // RNE
  return (u16)(u >> 16);
}

__device__ __forceinline__ unsigned int cvtpk(float lo, float hi) {
  unsigned int r;
  asm("v_cvt_pk_bf16_f32 %0, %1, %2" : "=v"(r) : "v"(lo), "v"(hi));
  return r;
}

__device__ __forceinline__ float fexp2(float x) {  // v_exp_f32 IS exp2
  float r;
  asm("v_exp_f32 %0, %1" : "=v"(r) : "v"(x));
  return r;
}

__device__ __forceinline__ void gload_lds16(const void* g, void* l) {
  __builtin_amdgcn_global_load_lds(
      (__attribute__((address_space(1))) void*)(g),
      (__attribute__((address_space(3))) void*)(l),
      16, 0, 0);
}

// ---------------- prep: z<4 -> W[z] transpose+cvt; z>=4 -> q/k/v fp32->bf16 ----------
__global__ __launch_bounds__(256) void wprep_kernel(const float* __restrict__ W0,
                                                    const float* __restrict__ W1,
                                                    const float* __restrict__ W2,
                                                    const float* __restrict__ W3,
                                                    u16* __restrict__ Wt,
                                                    const float* __restrict__ qin,
                                                    const float* __restrict__ kin,
                                                    const float* __restrict__ vin,
                                                    u16* __restrict__ Xq,
                                                    u16* __restrict__ Xk,
                                                    u16* __restrict__ Xv) {
  int z = blockIdx.z;
  if (z < 4) {
    __shared__ float tile[32][33];
    const float* W = (z == 0) ? W0 : (z == 1) ? W1 : (z == 2) ? W2 : W3;
    u16* out = Wt + (size_t)z * D_ * D_;
    int tx = threadIdx.x, ty = threadIdx.y;
    int x = blockIdx.x * 32 + tx;
    for (int j = 0; j < 32; j += 8)
      tile[ty + j][tx] = W[(size_t)(blockIdx.y * 32 + ty + j) * D_ + x];
    __syncthreads();
    int x2 = blockIdx.y * 32 + tx;
    for (int j = 0; j < 32; j += 8)
      out[(size_t)(blockIdx.x * 32 + ty + j) * D_ + x2] = f2bf(tile[tx][ty + j]);
  } else {
    int zz = z - 4;
    const float* src = (zz == 0) ? qin : (zz == 1) ? kin : vin;
    u16* dst = (zz == 0) ? Xq : (zz == 1) ? Xk : Xv;
    int bid = blockIdx.y * 32 + blockIdx.x;
    int t = threadIdx.y * 32 + threadIdx.x;
    const float4* s4 = (const float4*)src;
    for (int i = 0; i < 4; ++i) {
      int idx = bid * 1024 + i * 256 + t;
      float4 v4 = s4[idx];
      us4 o;
      o[0] = f2bf(v4.x); o[1] = f2bf(v4.y); o[2] = f2bf(v4.z); o[3] = f2bf(v4.w);
      ((us4*)dst)[idx] = o;
    }
  }
}

// ---------------- QKV GEMM: BK=64 (half the barriers), XOR-swizzled LDS tiles --------
// Tiles are [128][64] bf16 = 16 KB each; 128B row stride would be a bank-conflict trap
// (G4), so: linear gload_lds dest + pre-swizzled global source col (byte XOR
// ((row&7)<<4)) + the same XOR on ds_read (involution; pattern verified in attn STAGE).
// Two 32-k halves consumed sequentially per barrier period (same frag registers).
// z=2 (V) writes key columns PERMUTED within 64-key groups (attn PV b128 layout).
__global__ __launch_bounds__(256) void gemm_qkv(const u16* __restrict__ Xq,
                                                const u16* __restrict__ Xk,
                                                const u16* __restrict__ Xv,
                                                const u16* __restrict__ Wt,
                                                const float* __restrict__ bq,
                                                const float* __restrict__ bk,
                                                const float* __restrict__ bv,
                                                u16* __restrict__ Qh,
                                                u16* __restrict__ Kh,
                                                u16* __restrict__ Vt) {
  __shared__ u16 As[128 * 64];   // 16 KB
  __shared__ u16 Bs[128 * 64];   // 16 KB
  int fid = blockIdx.x;
  int xcd = fid & 7, ii = fid >> 3;
  int grp = ii >> 3, yy = ii & 7;
  int gg = xcd * 12 + grp;
  int z = gg >> 5;
  int xx = gg & 31;
  const u16* A = (z == 0) ? Xq : (z == 1) ? Xk : Xv;
  const u16* Bt = Wt + (size_t)z * D_ * D_;
  const float* bias = (z == 0) ? bq : (z == 1) ? bk : bv;
  u16* O = (z == 0) ? Qh : (z == 1) ? Kh : Vt;

  int tid = threadIdx.x;
  int lane = tid & 63, wave = tid >> 6;
  int m0 = xx * 128, n0 = yy * 128;
  int wr = wave >> 1, wc = wave & 1;
  int fr = lane & 15, fk = (lane >> 4) * 8;   // fk in elements; fk*2 = g*16 bytes

  f32x4 acc[4][4];
  const f32x4 vzero = {0.f, 0.f, 0.f, 0.f};
  for (int i = 0; i < 4; ++i)
    for (int j = 0; j < 4; ++j) acc[i][j] = vzero;

  for (int k0 = 0; k0 < D_; k0 += 64) {
    if (k0) __syncthreads();
    for (int i = 0; i < 4; ++i) {
      int base = ((i * 4 + wave) << 10);
      int ofs = base + lane * 16;
      int row = ofs >> 7;                       // 128 B per tile row
      int scolb = (ofs & 127) ^ ((row & 7) << 4);
      gload_lds16(A + (size_t)(m0 + row) * D_ + k0 + (scolb >> 1), (char*)As + base);
      gload_lds16(Bt + (size_t)(n0 + row) * D_ + k0 + (scolb >> 1), (char*)Bs + base);
    }
    __syncthreads();
    for (int kh = 0; kh < 2; ++kh) {
      bf16x8 af[4], bfr[4];
      for (int mi = 0; mi < 4; ++mi) {
        int row = wr * 64 + mi * 16 + fr;
        af[mi] = *(const bf16x8*)((const char*)As + row * 128 +
                                  ((kh * 64 + fk * 2) ^ ((row & 7) << 4)));
      }
      for (int ni = 0; ni < 4; ++ni) {
        int row = wc * 64 + ni * 16 + fr;
        bfr[ni] = *(const bf16x8*)((const char*)Bs + row * 128 +
                                   ((kh * 64 + fk * 2) ^ ((row & 7) << 4)));
      }
      for (int mi = 0; mi < 4; ++mi)
        for (int ni = 0; ni < 4; ++ni)
          acc[mi][ni] =
              __builtin_amdgcn_mfma_f32_16x16x32_bf16(af[mi], bfr[ni], acc[mi][ni], 0, 0, 0);
    }
  }

  if (z == 2) {  // Vt [B][H][DH][S], key columns permuted within 64-key groups
    for (int mi = 0; mi < 4; ++mi) {
      int rowb = m0 + wr * 64 + mi * 16 + (lane >> 4) * 4;
      int bb2 = rowb >> 11, s0 = rowb & (S_ - 1);
      int l0 = s0 & 63;
      int p_local = ((l0 >> 5) & 1) * 32 + ((l0 >> 2) & 3) * 8 + ((l0 >> 4) & 1) * 4;
      int col2 = (s0 & ~63) | p_local;   // s0%4==0 -> 4 consecutive keys stay together
      for (int ni = 0; ni < 4; ++ni) {
        int col = n0 + wc * 64 + ni * 16 + fr;
        int hh = col >> 6, dh = col & 63;
        float bv = bias[col];
        us4 pk;
        for (int r = 0; r < 4; ++r) pk[r] = f2bf(acc[mi][ni][r] + bv);
        *(us4*)(O + ((size_t)(bb2 * H_ + hh) * DH_ + dh) * S_ + col2) = pk;
      }
    }
  } else {       // Qh/Kh [B][H][S][DH]
    float scale = (z == 0) ? 0.125f : 1.0f;
    for (int mi = 0; mi < 4; ++mi) {
      int rowb = m0 + wr * 64 + mi * 16 + (lane >> 4) * 4;
      for (int ni = 0; ni < 4; ++ni) {
        int col = n0 + wc * 64 + ni * 16 + fr;
        int hh = col >> 6, dh = col & 63;
        float bv = bias[col];
        for (int r = 0; r < 4; ++r) {
          int row = rowb + r;
          int bb2 = row >> 11, s = row & (S_ - 1);
          O[((size_t)(bb2 * H_ + hh) * S_ + s) * DH_ + dh] =
              f2bf((acc[mi][ni][r] + bv) * scale);
        }
      }
    }
  }
}

// ---------------- output GEMM: BM=64 x BN=128, BK=64, XOR-swizzled tiles -------------
__global__ __launch_bounds__(256) void gemm_out(const u16* __restrict__ A,
                                                const u16* __restrict__ Bt,
                                                const float* __restrict__ bias,
                                                float* __restrict__ O) {
  __shared__ u16 As[64 * 64];    // 8 KB
  __shared__ u16 Bs[128 * 64];   // 16 KB
  int fid = blockIdx.x;
  int xcd = fid & 7, ii = fid >> 3;
  int grp = ii >> 3, yy = ii & 7;
  int gg = xcd * 8 + grp;
  int tid = threadIdx.x;
  int lane = tid & 63, wave = tid >> 6;
  int m0 = gg * 64, n0 = yy * 128;
  int fr = lane & 15, fk = (lane >> 4) * 8;

  f32x4 acc[4][2];
  const f32x4 vzero = {0.f, 0.f, 0.f, 0.f};
  for (int i = 0; i < 4; ++i)
    for (int j = 0; j < 2; ++j) acc[i][j] = vzero;

  for (int k0 = 0; k0 < D_; k0 += 64) {
    if (k0) __syncthreads();
    for (int i = 0; i < 2; ++i) {
      int base = ((i * 4 + wave) << 10);
      int ofs = base + lane * 16;
      int row = ofs >> 7;
      int scolb = (ofs & 127) ^ ((row & 7) << 4);
      gload_lds16(A + (size_t)(m0 + row) * D_ + k0 + (scolb >> 1), (char*)As + base);
    }
    for (int i = 0; i < 4; ++i) {
      int base = ((i * 4 + wave) << 10);
      int ofs = base + lane * 16;
      int row = ofs >> 7;
      int scolb = (ofs & 127) ^ ((row & 7) << 4);
      gload_lds16(Bt + (size_t)(n0 + row) * D_ + k0 + (scolb >> 1), (char*)Bs + base);
    }
    __syncthreads();
    for (int kh = 0; kh < 2; ++kh) {
      bf16x8 af[4], bfr[2];
      for (int mi = 0; mi < 4; ++mi) {
        int row = mi * 16 + fr;
        af[mi] = *(const bf16x8*)((const char*)As + row * 128 +
                                  ((kh * 64 + fk * 2) ^ ((row & 7) << 4)));
      }
      for (int ni = 0; ni < 2; ++ni) {
        int row = wave * 32 + ni * 16 + fr;
        bfr[ni] = *(const bf16x8*)((const char*)Bs + row * 128 +
                                   ((kh * 64 + fk * 2) ^ ((row & 7) << 4)));
      }
      for (int mi = 0; mi < 4; ++mi)
        for (int ni = 0; ni < 2; ++ni)
          acc[mi][ni] =
              __builtin_amdgcn_mfma_f32_16x16x32_bf16(af[mi], bfr[ni], acc[mi][ni], 0, 0, 0);
    }
  }

  for (int mi = 0; mi < 4; ++mi) {
    int rowb = m0 + mi * 16 + (lane >> 4) * 4;
    for (int ni = 0; ni < 2; ++ni) {
      int col = n0 + wave * 32 + ni * 16 + fr;
      float bv = bias[col];
      for (int r = 0; r < 4; ++r)
        O[(size_t)(rowb + r) * D_ + col] = acc[mi][ni][r] + bv;
    }
  }
}

// ---------------- flash attention v10 (unchanged from round 14/16) ----------------
__global__ __launch_bounds__(256, 4) void attn_kernel(const u16* __restrict__ Qh,
                                                      const u16* __restrict__ Kh,
                                                      const u16* __restrict__ Vt,
                                                      const float* __restrict__ relb,
                                                      u16* __restrict__ attnout) {
  __shared__ u16 KVs[2][2][4096];  // [kind][buf][64x64 bf16] = 32 KB

  int fid = blockIdx.x;
  int rr = fid >> 8, c = fid & 255;
  int j = c >> 3, e = c & 7;
  int s = (rr & 1) ? j : 31 - j;
  int h = (rr & 1) ? e + 8 : e;
  int b = rr >> 1;

  int w = threadIdx.x >> 6, lane = threadIdx.x & 63;
  int fr = lane & 15, g = lane >> 4;
  int q0w = s * 64 + w * 16;
  int qme = q0w + fr;
  int bh = b * H_ + h;
  int sx = (fr & 7) << 4;            // read-side XOR swizzle (bytes)

  int kind = w >> 1;
  int i0 = (w & 1) * 4;
  int srow_lo = lane >> 3;
  int scb = (lane & 7) * 16;

  const u16* Qb = Qh + ((size_t)bh * S_ + q0w) * DH_;
  bf16x8 qf0 = *(const bf16x8*)(Qb + fr * DH_ + 8 * g);
  bf16x8 qf1 = *(const bf16x8*)(Qb + fr * DH_ + 32 + 8 * g);

  const float* Bq = relb + (size_t)h * S_ * S_ + (size_t)qme * S_ + 4 * g;
  const float LOG2E = 1.44269504f;

  int T = s + 1;

  auto STAGE = [&](int buf, int kb) {
    for (int i = 0; i < 4; ++i) {
      int ii = i0 + i;
      int row = ii * 8 + srow_lo;
      int cbs = scb ^ ((row & 7) << 4);
      const u16* src;
      if (kind == 0)
        src = Kh + ((size_t)bh * S_ + kb + row) * DH_ + (cbs >> 1);
      else
        src = Vt + ((size_t)bh * DH_ + row) * S_ + kb + (cbs >> 1);
      gload_lds16(src, &KVs[kind][buf][ii * 512]);
    }
  };

  f32x4 acc[4];
  const f32x4 vzero = {0.f, 0.f, 0.f, 0.f};
  for (int f4 = 0; f4 < 4; ++f4) acc[f4] = vzero;
  float m = -1.0e4f, l = 0.f;   // per-lane partial l; first tile always rescales

  STAGE(0, 0);
  f32x4 bi[4], bn[4];
  for (int cc = 0; cc < 4; ++cc) bi[cc] = *(const f32x4*)(Bq + 16 * cc);
  __syncthreads();

  for (int t = 0; t < T; ++t) {
    int kb = t * 64;
    int buf = t & 1;
    bool diag = (t == T - 1);
    if (!diag) {
      STAGE(buf ^ 1, kb + 64);
      for (int cc = 0; cc < 4; ++cc) bn[cc] = *(const f32x4*)(Bq + kb + 64 + 16 * cc);
    }

    const u16* Kt = &KVs[0][buf][0];
    const u16* Vl = &KVs[1][buf][0];

    // swapped QK^T with bias as the C operand
    f32x4 sc[4];
    __builtin_amdgcn_s_setprio(1);
    for (int cc = 0; cc < 4; ++cc) {
      bf16x8 k0 = *(const bf16x8*)(Kt + (16 * cc + fr) * 64 + (((16 * g) ^ sx) >> 1));
      bf16x8 k1 = *(const bf16x8*)(Kt + (16 * cc + fr) * 64 + (((64 + 16 * g) ^ sx) >> 1));
      f32x4 z = __builtin_amdgcn_mfma_f32_16x16x32_bf16(k0, qf0, bi[cc], 0, 0, 0);
      z = __builtin_amdgcn_mfma_f32_16x16x32_bf16(k1, qf1, z, 0, 0, 0);
      sc[cc] = z;
    }
    __builtin_amdgcn_s_setprio(0);
    if (diag) {  // only the diagonal tile needs causal masking (bias already in)
      for (int cc = 0; cc < 4; ++cc)
        for (int r = 0; r < 4; ++r) {
          int key = kb + 16 * cc + 4 * g + r;
          sc[cc][r] = (key <= qme) ? sc[cc][r] : -1e30f;
        }
    }
    float pm = sc[0][0];
    for (int cc = 0; cc < 4; ++cc)
      for (int r = 0; r < 4; ++r) pm = fmaxf(pm, sc[cc][r]);
    pm = fmaxf(pm, __shfl_xor(pm, 16));
    pm = fmaxf(pm, __shfl_xor(pm, 32));
    if (!__all(pm - m <= 8.0f)) {
      float mn = fmaxf(m, pm);
      float corr = __expf(m - mn);
      m = mn;
      l *= corr;
      float c0 = __shfl(corr, 4 * g + 0);
      float c1 = __shfl(corr, 4 * g + 1);
      float c2 = __shfl(corr, 4 * g + 2);
      float c3 = __shfl(corr, 4 * g + 3);
      for (int f4 = 0; f4 < 4; ++f4) {
        acc[f4][0] *= c0; acc[f4][1] *= c1; acc[f4][2] *= c2; acc[f4][3] *= c3;
      }
    }
    float nms = m * -LOG2E;
    float rs = 0.f;
    for (int cc = 0; cc < 4; ++cc)
      for (int r = 0; r < 4; ++r) {
        sc[cc][r] = fexp2(fmaf(sc[cc][r], LOG2E, nms));
        rs += sc[cc][r];
      }
    l += rs;
    union { unsigned int w4[4]; bf16x8 v; } pp[2];
    for (int jj = 0; jj < 2; ++jj) {
      pp[jj].w4[0] = cvtpk(sc[2 * jj][0], sc[2 * jj][1]);
      pp[jj].w4[1] = cvtpk(sc[2 * jj][2], sc[2 * jj][3]);
      pp[jj].w4[2] = cvtpk(sc[2 * jj + 1][0], sc[2 * jj + 1][1]);
      pp[jj].w4[3] = cvtpk(sc[2 * jj + 1][2], sc[2 * jj + 1][3]);
    }
    // PV: V pre-permuted -> one b128 per (f4, jj), conflict-free
    __builtin_amdgcn_s_setprio(1);
    for (int f4 = 0; f4 < 4; ++f4) {
      for (int jj = 0; jj < 2; ++jj) {
        bf16x8 vv = *(const bf16x8*)(Vl + (f4 * 16 + fr) * 64 +
                                     (((jj * 64 + g * 16) ^ sx) >> 1));
        acc[f4] = __builtin_amdgcn_mfma_f32_16x16x32_bf16(pp[jj].v, vv, acc[f4], 0, 0, 0);
      }
    }
    __builtin_amdgcn_s_setprio(0);
    for (int cc = 0; cc < 4; ++cc) bi[cc] = bn[cc];
    __syncthreads();
  }

  // epilogue: reduce per-lane partial l across the 4 lanes sharing each q-row
  l += __shfl_xor(l, 16);
  l += __shfl_xor(l, 32);
  float il = 1.f / l;
  for (int r = 0; r < 4; ++r) {
    float ilr = __shfl(il, 4 * g + r);
    int qq = q0w + 4 * g + r;
    u16* ob = attnout + ((size_t)b * S_ + qq) * D_ + h * 64;
    for (int f4 = 0; f4 < 4; ++f4) ob[f4 * 16 + fr] = f2bf(acc[f4][r] * ilr);
  }
}

extern "C" void kernel_launch(void* const* d_in, const int* in_sizes, int n_in,
                              void* d_out, int out_size, void* d_ws, size_t ws_size,
                              hipStream_t stream) {
  const float* q = (const float*)d_in[0];
  const float* k = (const float*)d_in[1];
  const float* v = (const float*)d_in[2];
  const float* rb = (const float*)d_in[4];
  const float* Wq = (const float*)d_in[5];
  const float* bq = (const float*)d_in[6];
  const float* Wk = (const float*)d_in[7];
  const float* bk = (const float*)d_in[8];
  const float* Wv = (const float*)d_in[9];
  const float* bv = (const float*)d_in[10];
  const float* Wo = (const float*)d_in[11];
  const float* bo = (const float*)d_in[12];
  float* out = (float*)d_out;

  char* ws = (char*)d_ws;
  const size_t SZ = (size_t)M_ * D_ * 2;
  u16* Xq = (u16*)(ws);
  u16* Xk = (u16*)(ws + SZ);
  u16* Xv = (u16*)(ws + 2 * SZ);
  u16* Qh = (u16*)(ws + 3 * SZ);
  u16* Kh = (u16*)(ws + 4 * SZ);
  u16* Vt = (u16*)(ws + 5 * SZ);
  u16* Wt = (u16*)(ws + 6 * SZ);
  u16* Xb = Xq;

  wprep_kernel<<<dim3(32, 32, 7), dim3(32, 8), 0, stream>>>(Wq, Wk, Wv, Wo, Wt,
                                                            q, k, v, Xq, Xk, Xv);

  gemm_qkv<<<dim3(768), 256, 0, stream>>>(Xq, Xk, Xv, Wt, bq, bk, bv, Qh, Kh, Vt);

  attn_kernel<<<dim3(1024), 256, 0, stream>>>(Qh, Kh, Vt, rb, Xb);

  gemm_out<<<dim3(512), 256, 0, stream>>>(Xb, Wt + 3 * (size_t)D_ * D_, bo, out);
}